// Round 4
// baseline (338.656 us; speedup 1.0000x reference)
//
#include <hip/hip_runtime.h>
#include <hip/hip_fp16.h>
#include <cfloat>

#define NA 4096
#define NF 256
#define NH 8
#define DH 32

typedef _Float16 half8_t __attribute__((ext_vector_type(8)));
typedef _Float16 half4_t __attribute__((ext_vector_type(4)));
typedef float f32x4 __attribute__((ext_vector_type(4)));

// log2(e) / sqrt(2*DH) : folds 1/TP and natural->base2 exp into Q scale
#define QSCALE 0.1803368800112723f

// ---------------- cast f32 -> f16 (x and the three W's) ----------------
__global__ __launch_bounds__(256) void cast_kernel(
    const float* __restrict__ x, const float* __restrict__ wq,
    const float* __restrict__ wk, const float* __restrict__ wv,
    _Float16* __restrict__ xh, _Float16* __restrict__ whq,
    _Float16* __restrict__ whk, _Float16* __restrict__ whv) {
  const int XQ = NA * NF / 4;   // 262144 float4 quads in x
  const int WQ = NF * NF / 4;   // 16384 quads per W
  int i = blockIdx.x * blockDim.x + threadIdx.x;
  const float* src; _Float16* dst; int q;
  if (i < XQ)               { src = x;  dst = xh;  q = i; }
  else if (i < XQ + WQ)     { src = wq; dst = whq; q = i - XQ; }
  else if (i < XQ + 2 * WQ) { src = wk; dst = whk; q = i - XQ - WQ; }
  else if (i < XQ + 3 * WQ) { src = wv; dst = whv; q = i - XQ - 2 * WQ; }
  else return;
  float4 v = *(const float4*)(src + q * 4);
  half4_t h = { (_Float16)v.x, (_Float16)v.y, (_Float16)v.z, (_Float16)v.w };
  *(half4_t*)(dst + q * 4) = h;
}

// ---------------- QKV projection: y = x @ W^T + b ----------------
// grid (64 m-tiles, 12 = 4 n-tiles x 3 mats), 256 threads (4 waves).
// Wave w computes rows [m0+16w, +16) x cols [n0, n0+64).
// Q stored f16 row-major, pre-scaled by QSCALE. K f16 row-major.
// V stored TRANSPOSED: Vt[n][m] (256 x 4096) for contiguous PV A-frag loads.
__global__ __launch_bounds__(256) void proj_gemm(
    const _Float16* __restrict__ xh,
    const _Float16* __restrict__ whq, const _Float16* __restrict__ whk,
    const _Float16* __restrict__ whv,
    const float* __restrict__ bq, const float* __restrict__ bk,
    const float* __restrict__ bv,
    _Float16* __restrict__ Qh, _Float16* __restrict__ Kh,
    _Float16* __restrict__ Vt) {
  const int wave = threadIdx.x >> 6;
  const int lane = threadIdx.x & 63;
  const int lr = lane & 15;
  const int lg = lane >> 4;
  const int lg4 = lg * 4;
  const int mt = blockIdx.x;
  const int nb = blockIdx.y & 3;
  const int mat = blockIdx.y >> 2;
  const _Float16* W = (mat == 0) ? whq : (mat == 1) ? whk : whv;
  const float* bias = (mat == 0) ? bq : (mat == 1) ? bk : bv;
  const int m0 = mt * 64 + wave * 16;
  const int n0 = nb * 64;

  f32x4 z = {0.f, 0.f, 0.f, 0.f};
  f32x4 acc[4] = {z, z, z, z};
  for (int k0 = 0; k0 < NF; k0 += 32) {
    half8_t afrag = *(const half8_t*)(xh + (m0 + lr) * NF + k0 + lg * 8);
#pragma unroll
    for (int nt = 0; nt < 4; nt++) {
      half8_t bfrag = *(const half8_t*)(W + (n0 + nt * 16 + lr) * NF + k0 + lg * 8);
      acc[nt] = __builtin_amdgcn_mfma_f32_16x16x32_f16(afrag, bfrag, acc[nt], 0, 0, 0);
    }
  }
#pragma unroll
  for (int nt = 0; nt < 4; nt++) {
    const int n = n0 + nt * 16 + lr;   // C col = lane&15
    const float b = bias[n];
    if (mat == 0) {
#pragma unroll
      for (int j = 0; j < 4; j++)
        Qh[(m0 + lg4 + j) * NF + n] = (_Float16)((acc[nt][j] + b) * QSCALE);
    } else if (mat == 1) {
#pragma unroll
      for (int j = 0; j < 4; j++)
        Kh[(m0 + lg4 + j) * NF + n] = (_Float16)(acc[nt][j] + b);
    } else {
      half4_t hv = { (_Float16)(acc[nt][0] + b), (_Float16)(acc[nt][1] + b),
                     (_Float16)(acc[nt][2] + b), (_Float16)(acc[nt][3] + b) };
      *(half4_t*)(Vt + n * NA + m0 + lg4) = hv;  // Vt[n][m0+lg4 .. +3]
    }
  }
}

// ---------------- flash attention ----------------
// grid = 256 blocks (q-tiles of 16 rows), 512 threads = 8 waves = 8 heads.
// Swapped QK^T: S^T = mfma(K_tile, Q) -> lane holds S^T[key=(l>>4)*4+j][q=l&15].
// That C-layout IS the B-frag layout for O^T = V^T @ P^T (mfma 16x16x16).
__global__ __launch_bounds__(512) void attn_kernel(
    const _Float16* __restrict__ Qh, const _Float16* __restrict__ Kh,
    const _Float16* __restrict__ Vt, const int* __restrict__ mask,
    float* __restrict__ out) {
  const int h = threadIdx.x >> 6;
  const int lane = threadIdx.x & 63;
  const int lq = lane & 15;
  const int lg = lane >> 4;
  const int q0 = blockIdx.x * 16;

  // Q B-frag: col q = lane&15, k(d) = lg*8 + j  (16B contiguous)
  const half8_t qfrag = *(const half8_t*)(Qh + (q0 + lq) * NF + h * DH + lg * 8);
  const _Float16* Vh = Vt + h * DH * NA;
  const int* mrow = mask + (q0 + lq) * NA;

  f32x4 z = {0.f, 0.f, 0.f, 0.f};
  f32x4 o0 = z, o1 = z;           // O^T accum: d-tiles [0,16) and [16,32)
  float mrun = -FLT_MAX, srun = 0.f;

  for (int kt = 0; kt < NA; kt += 32) {
    // K A-frags: row key = lane&15, k(d) = lg*8+j
    half8_t kf0 = *(const half8_t*)(Kh + (kt + lq) * NF + h * DH + lg * 8);
    half8_t kf1 = *(const half8_t*)(Kh + (kt + 16 + lq) * NF + h * DH + lg * 8);
    f32x4 st0 = __builtin_amdgcn_mfma_f32_16x16x32_f16(kf0, qfrag, z, 0, 0, 0);
    f32x4 st1 = __builtin_amdgcn_mfma_f32_16x16x32_f16(kf1, qfrag, z, 0, 0, 0);

    // mask[q][key]: lane needs keys kt + 16t + lg*4 + j at row q0+lq
    int4 mk0 = *(const int4*)(mrow + kt + lg * 4);
    int4 mk1 = *(const int4*)(mrow + kt + 16 + lg * 4);
    float s[8];
    s[0] = mk0.x ? -FLT_MAX : st0[0];
    s[1] = mk0.y ? -FLT_MAX : st0[1];
    s[2] = mk0.z ? -FLT_MAX : st0[2];
    s[3] = mk0.w ? -FLT_MAX : st0[3];
    s[4] = mk1.x ? -FLT_MAX : st1[0];
    s[5] = mk1.y ? -FLT_MAX : st1[1];
    s[6] = mk1.z ? -FLT_MAX : st1[2];
    s[7] = mk1.w ? -FLT_MAX : st1[3];

    // online softmax (exp2 domain; scale folded into Q)
    float pm = s[0];
#pragma unroll
    for (int j = 1; j < 8; j++) pm = fmaxf(pm, s[j]);
    pm = fmaxf(pm, __shfl_xor(pm, 16));
    pm = fmaxf(pm, __shfl_xor(pm, 32));
    float mnew = fmaxf(mrun, pm);
    float alpha = __builtin_exp2f(mrun - mnew);
    float p[8];
    float ps = 0.f;
#pragma unroll
    for (int j = 0; j < 8; j++) { p[j] = __builtin_exp2f(s[j] - mnew); ps += p[j]; }
    ps += __shfl_xor(ps, 16);
    ps += __shfl_xor(ps, 32);
    srun = srun * alpha + ps;
    mrun = mnew;
    o0 = o0 * alpha;
    o1 = o1 * alpha;

    // P^T B-frags (C-layout == B-layout): col q = lane&15, k(key) = lg*4+j
    half4_t p0 = { (_Float16)p[0], (_Float16)p[1], (_Float16)p[2], (_Float16)p[3] };
    half4_t p1 = { (_Float16)p[4], (_Float16)p[5], (_Float16)p[6], (_Float16)p[7] };

    // V^T A-frags: row d = lane&15 (+16 for o1), k(key) = lg*4+j (8B contiguous)
    half4_t v00 = *(const half4_t*)(Vh + lq * NA + kt + lg * 4);
    half4_t v01 = *(const half4_t*)(Vh + lq * NA + kt + 16 + lg * 4);
    half4_t v10 = *(const half4_t*)(Vh + (16 + lq) * NA + kt + lg * 4);
    half4_t v11 = *(const half4_t*)(Vh + (16 + lq) * NA + kt + 16 + lg * 4);
    o0 = __builtin_amdgcn_mfma_f32_16x16x16f16(v00, p0, o0, 0, 0, 0);
    o0 = __builtin_amdgcn_mfma_f32_16x16x16f16(v01, p1, o0, 0, 0, 0);
    o1 = __builtin_amdgcn_mfma_f32_16x16x16f16(v10, p0, o1, 0, 0, 0);
    o1 = __builtin_amdgcn_mfma_f32_16x16x16f16(v11, p1, o1, 0, 0, 0);
  }

  const float inv = 1.f / srun;
  float* orow = out + (q0 + lq) * NF + h * DH;
  float4 r0 = { o0[0] * inv, o0[1] * inv, o0[2] * inv, o0[3] * inv };
  float4 r1 = { o1[0] * inv, o1[1] * inv, o1[2] * inv, o1[3] * inv };
  *(float4*)(orow + lg * 4) = r0;
  *(float4*)(orow + 16 + lg * 4) = r1;
}

extern "C" void kernel_launch(void* const* d_in, const int* in_sizes, int n_in,
                              void* d_out, int out_size, void* d_ws, size_t ws_size,
                              hipStream_t stream) {
  const float* x  = (const float*)d_in[0];
  const int* mask = (const int*)d_in[1];   // bool mask, assumed staged as int32
  const float* Wq = (const float*)d_in[2];
  const float* bq = (const float*)d_in[3];
  const float* Wk = (const float*)d_in[4];
  const float* bk = (const float*)d_in[5];
  const float* Wv = (const float*)d_in[6];
  const float* bv = (const float*)d_in[7];
  float* out = (float*)d_out;

  char* ws = (char*)d_ws;   // needs ~8.4 MB
  _Float16* xh  = (_Float16*)(ws + 0);         // 4096x256   (2 MB)
  _Float16* whq = (_Float16*)(ws + 2097152);   // 256x256    (128 KB)
  _Float16* whk = (_Float16*)(ws + 2228224);
  _Float16* whv = (_Float16*)(ws + 2359296);
  _Float16* Qh  = (_Float16*)(ws + 2490368);   // 4096x256 f16, pre-scaled
  _Float16* Kh  = (_Float16*)(ws + 4587520);   // 4096x256 f16
  _Float16* Vt  = (_Float16*)(ws + 6684672);   // 256x4096 f16 (V transposed)

  cast_kernel<<<1216, 256, 0, stream>>>(x, Wq, Wk, Wv, xh, whq, whk, whv);
  proj_gemm<<<dim3(64, 12), 256, 0, stream>>>(xh, whq, whk, whv, bq, bk, bv,
                                              Qh, Kh, Vt);
  attn_kernel<<<dim3(NA / 16), 512, 0, stream>>>(Qh, Kh, Vt, mask, out);
}